// Round 1
// baseline (577.414 us; speedup 1.0000x reference)
//
#include <hip/hip_runtime.h>

#define NN 20000
#define DD 128
#define EE 640000
#define TSEQ 12
#define PRES 0.1f

__device__ __forceinline__ void fma4(float4& acc, float a, const float4& w) {
  acc.x += a * w.x; acc.y += a * w.y; acc.z += a * w.z; acc.w += a * w.w;
}

// ---------------- setup kernels ----------------
__global__ void k_init(float* __restrict__ deg, int* __restrict__ counts) {
  int i = blockIdx.x * blockDim.x + threadIdx.x;
  if (i < NN) { deg[i] = 1.0f; counts[i] = 0; }
}

__global__ void k_edge_deg(const int* __restrict__ src, const int* __restrict__ dst,
                           const float* __restrict__ w,
                           float* __restrict__ deg, int* __restrict__ counts) {
  int e = blockIdx.x * blockDim.x + threadIdx.x;
  if (e < EE) {
    int d = dst[e];
    atomicAdd(&deg[d], w[e]);
    atomicAdd(&counts[d], 1);
  }
}

__global__ void k_dinv(const float* __restrict__ deg, float* __restrict__ dinv) {
  int i = blockIdx.x * blockDim.x + threadIdx.x;
  if (i < NN) { float g = deg[i]; dinv[i] = (g > 0.f) ? rsqrtf(g) : 0.f; }
}

__global__ void k_scan1(const int* __restrict__ counts, int* __restrict__ lpre,
                        int* __restrict__ bsum) {
  __shared__ int s[256];
  int t = threadIdx.x, i = blockIdx.x * 256 + t;
  int v = (i < NN) ? counts[i] : 0;
  s[t] = v;
  __syncthreads();
  for (int off = 1; off < 256; off <<= 1) {
    int add = (t >= off) ? s[t - off] : 0;
    __syncthreads();
    s[t] += add;
    __syncthreads();
  }
  if (i < NN) lpre[i] = s[t] - v;
  if (t == 255) bsum[blockIdx.x] = s[255];
}

__global__ void k_scan2(const int* __restrict__ bsum, int* __restrict__ bpre, int nb) {
  __shared__ int s[128];
  int t = threadIdx.x;
  int v = (t < nb) ? bsum[t] : 0;
  s[t] = v;
  __syncthreads();
  for (int off = 1; off < 128; off <<= 1) {
    int add = (t >= off) ? s[t - off] : 0;
    __syncthreads();
    s[t] += add;
    __syncthreads();
  }
  bpre[t] = s[t] - v;
}

__global__ void k_scan3(const int* __restrict__ lpre, const int* __restrict__ bpre,
                        int* __restrict__ offs, int* __restrict__ cursor) {
  int i = blockIdx.x * blockDim.x + threadIdx.x;
  if (i < NN) { int o = lpre[i] + bpre[i >> 8]; offs[i] = o; cursor[i] = o; }
}

__global__ void k_scatter(const int* __restrict__ src, const int* __restrict__ dst,
                          const float* __restrict__ w, const float* __restrict__ dinv,
                          int* __restrict__ cursor,
                          int* __restrict__ csr_src, float* __restrict__ csr_norm) {
  int e = blockIdx.x * blockDim.x + threadIdx.x;
  if (e < EE) {
    int s = src[e], d = dst[e];
    int slot = atomicAdd(&cursor[d], 1);
    csr_src[slot] = s;
    csr_norm[slot] = dinv[s] * w[e] * dinv[d];
  }
}

// out[k*IR + d] = in[d*IC + k]   (IR = in rows = 128, IC = in cols = K)
__global__ void k_transpose(const float* __restrict__ in, float* __restrict__ out,
                            int IR, int IC) {
  int i = blockIdx.x * blockDim.x + threadIdx.x;
  if (i < IR * IC) {
    int k = i / IR, d = i - k * IR;
    out[i] = in[d * IC + k];
  }
}

// ---------------- GEMM: out[n][d] = sum_k A[n][k] * Wt[k][d] (+bias) ----------------
#define G_TN 6
#define G_BN 96   // 16 groups * 6 nodes

__global__ __launch_bounds__(256) void k_gemm(
    const float* __restrict__ a0, int s0,
    const float* __restrict__ a1, int s1,
    const float* __restrict__ a2, int s2,
    int nparts,
    const float* __restrict__ Wt,     // [nparts*128][128]
    const float* __restrict__ bias,   // [128] or nullptr
    float* __restrict__ out)
{
  __shared__ float Ws[128 * 128];     // 64 KB, one K-chunk at a time
  const int t = threadIdx.x;
  const int dq = t & 15;              // d quads at 4*dq and 64+4*dq (2-way bank alias max)
  const int ng = t >> 4;
  const int n_base = blockIdx.x * G_BN + ng * G_TN;

  float4 acc0[G_TN], acc1[G_TN];
  #pragma unroll
  for (int i = 0; i < G_TN; ++i) {
    acc0[i] = make_float4(0.f, 0.f, 0.f, 0.f);
    acc1[i] = make_float4(0.f, 0.f, 0.f, 0.f);
  }

  for (int p = 0; p < nparts; ++p) {
    const float4* wsrc = (const float4*)(Wt + p * 16384);
    float4* wdst = (float4*)Ws;
    #pragma unroll
    for (int it = 0; it < 16; ++it) wdst[it * 256 + t] = wsrc[it * 256 + t];
    __syncthreads();

    const float* ap; int as;
    if (p == 0) { ap = a0; as = s0; }
    else if (p == 1) { ap = a1; as = s1; }
    else { ap = a2; as = s2; }
    const float* rp[G_TN];
    #pragma unroll
    for (int i = 0; i < G_TN; ++i) {
      int r = n_base + i; if (r >= NN) r = NN - 1;
      rp[i] = ap + (size_t)r * as;
    }

    for (int k = 0; k < 128; k += 4) {
      float4 av[G_TN];
      #pragma unroll
      for (int i = 0; i < G_TN; ++i) av[i] = *(const float4*)(rp[i] + k);
      #pragma unroll
      for (int j = 0; j < 4; ++j) {
        const float4 w0 = *(const float4*)&Ws[(k + j) * 128 + 4 * dq];
        const float4 w1 = *(const float4*)&Ws[(k + j) * 128 + 64 + 4 * dq];
        #pragma unroll
        for (int i = 0; i < G_TN; ++i) {
          float a = (j == 0) ? av[i].x : (j == 1) ? av[i].y : (j == 2) ? av[i].z : av[i].w;
          fma4(acc0[i], a, w0);
          fma4(acc1[i], a, w1);
        }
      }
    }
    __syncthreads();
  }

  float4 b0 = make_float4(0.f,0.f,0.f,0.f), b1 = b0;
  if (bias) {
    b0 = *(const float4*)&bias[4 * dq];
    b1 = *(const float4*)&bias[64 + 4 * dq];
  }
  #pragma unroll
  for (int i = 0; i < G_TN; ++i) {
    int r = n_base + i;
    if (r < NN) {
      float4 o0 = make_float4(acc0[i].x + b0.x, acc0[i].y + b0.y,
                              acc0[i].z + b0.z, acc0[i].w + b0.w);
      float4 o1 = make_float4(acc1[i].x + b1.x, acc1[i].y + b1.y,
                              acc1[i].z + b1.z, acc1[i].w + b1.w);
      *(float4*)(out + (size_t)r * DD + 4 * dq) = o0;
      *(float4*)(out + (size_t)r * DD + 64 + 4 * dq) = o1;
    }
  }
}

// ---------------- aggregation: out = (1-p)*(segsum + self + b) + p*tin ----------------
__global__ __launch_bounds__(256) void k_agg(
    const float* __restrict__ x, const float* __restrict__ tin,
    const int* __restrict__ offs, const int* __restrict__ ends,
    const int* __restrict__ csr_src, const float* __restrict__ csr_norm,
    const float* __restrict__ dinv, const float* __restrict__ bias,
    float* __restrict__ out)
{
  const int t = threadIdx.x;
  const int dq = t & 31;          // float4 column
  const int nl = t >> 5;          // 8 nodes per block
  const int n = blockIdx.x * 8 + nl;
  if (n >= NN) return;
  const float4* x4 = (const float4*)x;
  const float di = dinv[n];
  float4 acc = make_float4(0.f, 0.f, 0.f, 0.f);
  fma4(acc, di * di, x4[(size_t)n * 32 + dq]);   // self loop (w=1)

  const int e0 = offs[n], e1 = ends[n];
  int j = e0;
  for (; j + 4 <= e1; j += 4) {
    int sa = csr_src[j], sb = csr_src[j + 1], sc = csr_src[j + 2], sd = csr_src[j + 3];
    float wa = csr_norm[j], wb = csr_norm[j + 1], wc = csr_norm[j + 2], wd = csr_norm[j + 3];
    float4 va = x4[(size_t)sa * 32 + dq];
    float4 vb = x4[(size_t)sb * 32 + dq];
    float4 vc = x4[(size_t)sc * 32 + dq];
    float4 vd = x4[(size_t)sd * 32 + dq];
    fma4(acc, wa, va); fma4(acc, wb, vb); fma4(acc, wc, vc); fma4(acc, wd, vd);
  }
  for (; j < e1; ++j) {
    int sa = csr_src[j]; float wa = csr_norm[j];
    fma4(acc, wa, x4[(size_t)sa * 32 + dq]);
  }

  const float4 b = *(const float4*)&bias[4 * dq];
  const float4 ti = ((const float4*)tin)[(size_t)n * 32 + dq];
  float4 o;
  o.x = (1.f - PRES) * (acc.x + b.x) + PRES * ti.x;
  o.y = (1.f - PRES) * (acc.y + b.y) + PRES * ti.y;
  o.z = (1.f - PRES) * (acc.z + b.z) + PRES * ti.z;
  o.w = (1.f - PRES) * (acc.w + b.w) + PRES * ti.w;
  ((float4*)out)[(size_t)n * 32 + dq] = o;
}

// ---------------- launch ----------------
extern "C" void kernel_launch(void* const* d_in, const int* in_sizes, int n_in,
                              void* d_out, int out_size, void* d_ws, size_t ws_size,
                              hipStream_t stream) {
  const float* demand = (const float*)d_in[0];
  const float* supply = (const float*)d_in[1];
  const int*   eidx   = (const int*)d_in[5];
  const float* eattr  = (const float*)d_in[6];
  const float* emb    = (const float*)d_in[10];
  const float* fuse_W = (const float*)d_in[11];
  const float* fuse_b = (const float*)d_in[12];
  const float* gcn_W  = (const float*)d_in[13];
  const float* gcn_b  = (const float*)d_in[14];
  float* outp = (float*)d_out;

  char* ws = (char*)d_ws;
  size_t o = 0;
  auto alloc = [&](size_t bytes) {
    char* p = ws + o;
    o += (bytes + 255) & ~(size_t)255;
    return p;
  };
  float* deg      = (float*)alloc((size_t)NN * 4);
  float* dinv     = (float*)alloc((size_t)NN * 4);
  int*   counts   = (int*)alloc((size_t)NN * 4);
  int*   lpre     = (int*)alloc((size_t)NN * 4);
  int*   bsum     = (int*)alloc(512);
  int*   bpre     = (int*)alloc(512);
  int*   offs     = (int*)alloc((size_t)NN * 4);
  int*   cursor   = (int*)alloc((size_t)NN * 4);
  int*   csr_src  = (int*)alloc((size_t)EE * 4);
  float* csr_norm = (float*)alloc((size_t)EE * 4);
  float* fuse_Wt  = (float*)alloc((size_t)384 * 128 * 4);
  float* gWt      = (float*)alloc((size_t)3 * 128 * 128 * 4);
  float* temp0    = (float*)alloc((size_t)NN * DD * 4);
  float* temp1    = (float*)alloc((size_t)NN * DD * 4);
  float* xbuf     = (float*)alloc((size_t)NN * DD * 4);

  const int* srcv = eidx;        // edge_index[0]
  const int* dstv = eidx + EE;   // edge_index[1]

  const int NB = (NN + 255) / 256;   // 79
  const int EB = (EE + 255) / 256;   // 2500

  k_init<<<NB, 256, 0, stream>>>(deg, counts);
  k_edge_deg<<<EB, 256, 0, stream>>>(srcv, dstv, eattr, deg, counts);
  k_dinv<<<NB, 256, 0, stream>>>(deg, dinv);
  k_scan1<<<NB, 256, 0, stream>>>(counts, lpre, bsum);
  k_scan2<<<1, 128, 0, stream>>>(bsum, bpre, NB);
  k_scan3<<<NB, 256, 0, stream>>>(lpre, bpre, offs, cursor);
  k_scatter<<<EB, 256, 0, stream>>>(srcv, dstv, eattr, dinv, cursor, csr_src, csr_norm);

  k_transpose<<<(128 * 384 + 255) / 256, 256, 0, stream>>>(fuse_W, fuse_Wt, 128, 384);
  for (int l = 0; l < 3; ++l)
    k_transpose<<<(128 * 128 + 255) / 256, 256, 0, stream>>>(gcn_W + l * 16384,
                                                             gWt + l * 16384, 128, 128);

  const int GB = (NN + G_BN - 1) / G_BN;  // 209
  // fused = [emb | demand[:, -1] | supply[:, -1]] @ fuse_W^T + fuse_b
  k_gemm<<<GB, 256, 0, stream>>>(emb, 128,
                                 demand + 11 * 128, TSEQ * 128,
                                 supply + 11 * 128, TSEQ * 128,
                                 3, fuse_Wt, fuse_b, temp0);

  const int AB = (NN + 7) / 8;  // 2500
  // layer 0: temp0 -> temp1
  k_gemm<<<GB, 256, 0, stream>>>(temp0, 128, temp0, 128, temp0, 128, 1, gWt, nullptr, xbuf);
  k_agg<<<AB, 256, 0, stream>>>(xbuf, temp0, offs, cursor, csr_src, csr_norm, dinv, gcn_b, temp1);
  // layer 1: temp1 -> temp0
  k_gemm<<<GB, 256, 0, stream>>>(temp1, 128, temp1, 128, temp1, 128, 1, gWt + 16384, nullptr, xbuf);
  k_agg<<<AB, 256, 0, stream>>>(xbuf, temp1, offs, cursor, csr_src, csr_norm, dinv, gcn_b + 128, temp0);
  // layer 2: temp0 -> d_out
  k_gemm<<<GB, 256, 0, stream>>>(temp0, 128, temp0, 128, temp0, 128, 1, gWt + 32768, nullptr, xbuf);
  k_agg<<<AB, 256, 0, stream>>>(xbuf, temp0, offs, cursor, csr_src, csr_norm, dinv, gcn_b + 256, outp);
}

// Round 2
// 502.943 us; speedup vs baseline: 1.1481x; 1.1481x over previous
//
#include <hip/hip_runtime.h>
#include <hip/hip_fp16.h>

#define NN 20000
#define DD 128
#define EE 640000
#define TSEQ 12
#define PRES 0.1f

__device__ __forceinline__ void fma4(float4& acc, float a, const float4& w) {
  acc.x += a * w.x; acc.y += a * w.y; acc.z += a * w.z; acc.w += a * w.w;
}

__device__ __forceinline__ float4 h8_to_f4(uint2 v) {
  union { unsigned u; __half2 h; } a, b;
  a.u = v.x; b.u = v.y;
  float2 fa = __half22float2(a.h);
  float2 fb = __half22float2(b.h);
  return make_float4(fa.x, fa.y, fb.x, fb.y);
}

__device__ __forceinline__ uint2 f4_to_h8(float4 o) {
  union { unsigned u; __half2 h; } a, b;
  a.h = __floats2half2_rn(o.x, o.y);
  b.h = __floats2half2_rn(o.z, o.w);
  uint2 r; r.x = a.u; r.y = b.u;
  return r;
}

// ---------------- setup kernels ----------------
__global__ void k_init(float* __restrict__ deg, int* __restrict__ counts) {
  int i = blockIdx.x * blockDim.x + threadIdx.x;
  if (i < NN) { deg[i] = 1.0f; counts[i] = 0; }
}

__global__ void k_edge_deg(const int* __restrict__ dst, const float* __restrict__ w,
                           float* __restrict__ deg, int* __restrict__ counts) {
  int e = blockIdx.x * blockDim.x + threadIdx.x;
  if (e < EE) {
    int d = dst[e];
    atomicAdd(&deg[d], w[e]);
    atomicAdd(&counts[d], 1);
  }
}

__global__ void k_scan1(const int* __restrict__ counts, int* __restrict__ lpre,
                        int* __restrict__ bsum) {
  __shared__ int s[256];
  int t = threadIdx.x, i = blockIdx.x * 256 + t;
  int v = (i < NN) ? counts[i] : 0;
  s[t] = v;
  __syncthreads();
  for (int off = 1; off < 256; off <<= 1) {
    int add = (t >= off) ? s[t - off] : 0;
    __syncthreads();
    s[t] += add;
    __syncthreads();
  }
  if (i < NN) lpre[i] = s[t] - v;
  if (t == 255) bsum[blockIdx.x] = s[255];
}

__global__ void k_scan2(const int* __restrict__ bsum, int* __restrict__ bpre, int nb) {
  __shared__ int s[128];
  int t = threadIdx.x;
  int v = (t < nb) ? bsum[t] : 0;
  s[t] = v;
  __syncthreads();
  for (int off = 1; off < 128; off <<= 1) {
    int add = (t >= off) ? s[t - off] : 0;
    __syncthreads();
    s[t] += add;
    __syncthreads();
  }
  bpre[t] = s[t] - v;
}

// also computes dinv (elementwise pass over nodes anyway)
__global__ void k_scan3(const int* __restrict__ lpre, const int* __restrict__ bpre,
                        const float* __restrict__ deg,
                        int* __restrict__ offs, int* __restrict__ cursor,
                        float* __restrict__ dinv) {
  int i = blockIdx.x * blockDim.x + threadIdx.x;
  if (i < NN) {
    int o = lpre[i] + bpre[i >> 8];
    offs[i] = o; cursor[i] = o;
    float g = deg[i];
    dinv[i] = (g > 0.f) ? rsqrtf(g) : 0.f;
  }
}

__global__ void k_scatter(const int* __restrict__ src, const int* __restrict__ dst,
                          const float* __restrict__ w, const float* __restrict__ dinv,
                          int* __restrict__ cursor,
                          int* __restrict__ csr_src, float* __restrict__ csr_norm) {
  int e = blockIdx.x * blockDim.x + threadIdx.x;
  if (e < EE) {
    int s = src[e], d = dst[e];
    int slot = atomicAdd(&cursor[d], 1);
    csr_src[slot] = s;
    csr_norm[slot] = dinv[s] * w[e] * dinv[d];
  }
}

// one kernel: fuse_Wt[k*128+d] = fuse_W[d*384+k]; gWt[l][k*128+d] = gcn_W[l][d*128+k]
__global__ void k_transpose_all(const float* __restrict__ fuse_W,
                                const float* __restrict__ gcn_W,
                                float* __restrict__ fuse_Wt, float* __restrict__ gWt) {
  int i = blockIdx.x * blockDim.x + threadIdx.x;
  if (i < 49152) {
    int k = i >> 7, d = i & 127;
    fuse_Wt[i] = fuse_W[d * 384 + k];
  } else if (i < 98304) {
    int j = i - 49152;
    int l = j >> 14, jj = j & 16383;
    int k = jj >> 7, d = jj & 127;
    gWt[j] = gcn_W[l * 16384 + d * 128 + k];
  }
}

// ---------------- GEMM: out[n][d] = sum_k A[n][k] * Wt[k][d] (+bias) ----------------
#define G_TN 2
#define G_BN 32   // 16 dq-groups * 2 rows

__global__ __launch_bounds__(256, 4) void k_gemm(
    const float* __restrict__ a0, int s0,
    const float* __restrict__ a1, int s1,
    const float* __restrict__ a2, int s2,
    int nparts,
    const float* __restrict__ Wt,     // [nparts*128][128] (k-major)
    const float* __restrict__ bias,   // [128] or nullptr
    float* __restrict__ outf,         // fp32 out or nullptr
    uint2* __restrict__ outh)         // fp16-packed out or nullptr
{
  __shared__ float Ws[64 * 128];      // 32 KB: one 64-k chunk
  const int t = threadIdx.x;
  const int dq = t & 15;              // d quads at 4*dq and 64+4*dq
  const int ng = t >> 4;
  const int n_base = blockIdx.x * G_BN + ng * G_TN;

  float4 acc0[G_TN], acc1[G_TN];
  #pragma unroll
  for (int i = 0; i < G_TN; ++i) {
    acc0[i] = make_float4(0.f, 0.f, 0.f, 0.f);
    acc1[i] = make_float4(0.f, 0.f, 0.f, 0.f);
  }

  for (int p = 0; p < nparts; ++p) {
    const float* ap; int as;
    if (p == 0) { ap = a0; as = s0; }
    else if (p == 1) { ap = a1; as = s1; }
    else { ap = a2; as = s2; }
    const float* rp[G_TN];
    #pragma unroll
    for (int i = 0; i < G_TN; ++i) {
      int r = n_base + i; if (r >= NN) r = NN - 1;
      rp[i] = ap + (size_t)r * as;
    }

    for (int c = 0; c < 2; ++c) {     // two 64-k chunks per 128-k part
      const float4* wsrc = (const float4*)(Wt + (p * 128 + c * 64) * 128);
      float4* wdst = (float4*)Ws;
      #pragma unroll
      for (int it = 0; it < 8; ++it) wdst[it * 256 + t] = wsrc[it * 256 + t];
      __syncthreads();

      const int ks = c * 64;
      for (int k = 0; k < 64; k += 4) {
        float4 av[G_TN];
        #pragma unroll
        for (int i = 0; i < G_TN; ++i) av[i] = *(const float4*)(rp[i] + ks + k);
        #pragma unroll
        for (int j = 0; j < 4; ++j) {
          const float4 w0 = *(const float4*)&Ws[(k + j) * 128 + 4 * dq];
          const float4 w1 = *(const float4*)&Ws[(k + j) * 128 + 64 + 4 * dq];
          #pragma unroll
          for (int i = 0; i < G_TN; ++i) {
            float a = (j == 0) ? av[i].x : (j == 1) ? av[i].y : (j == 2) ? av[i].z : av[i].w;
            fma4(acc0[i], a, w0);
            fma4(acc1[i], a, w1);
          }
        }
      }
      __syncthreads();
    }
  }

  float4 b0 = make_float4(0.f,0.f,0.f,0.f), b1 = b0;
  if (bias) {
    b0 = *(const float4*)&bias[4 * dq];
    b1 = *(const float4*)&bias[64 + 4 * dq];
  }
  #pragma unroll
  for (int i = 0; i < G_TN; ++i) {
    int r = n_base + i;
    if (r < NN) {
      float4 o0 = make_float4(acc0[i].x + b0.x, acc0[i].y + b0.y,
                              acc0[i].z + b0.z, acc0[i].w + b0.w);
      float4 o1 = make_float4(acc1[i].x + b1.x, acc1[i].y + b1.y,
                              acc1[i].z + b1.z, acc1[i].w + b1.w);
      if (outf) {
        *(float4*)(outf + (size_t)r * DD + 4 * dq) = o0;
        *(float4*)(outf + (size_t)r * DD + 64 + 4 * dq) = o1;
      } else {
        outh[(size_t)r * 32 + dq] = f4_to_h8(o0);
        outh[(size_t)r * 32 + 16 + dq] = f4_to_h8(o1);
      }
    }
  }
}

// ---------------- aggregation: out = (1-p)*(segsum + self + b) + p*tin ----------------
// x is fp16-packed: 32 x uint2 per row (4 halves each)
__global__ __launch_bounds__(256) void k_agg(
    const uint2* __restrict__ x2, const float* __restrict__ tin,
    const int* __restrict__ offs, const int* __restrict__ ends,
    const int* __restrict__ csr_src, const float* __restrict__ csr_norm,
    const float* __restrict__ dinv, const float* __restrict__ bias,
    float* __restrict__ out)
{
  const int t = threadIdx.x;
  const int dq = t & 31;          // uint2 column (4 dims)
  const int nl = t >> 5;          // 8 nodes per block
  const int n = blockIdx.x * 8 + nl;
  if (n >= NN) return;
  const float di = dinv[n];
  float4 acc = make_float4(0.f, 0.f, 0.f, 0.f);
  fma4(acc, di * di, h8_to_f4(x2[(size_t)n * 32 + dq]));   // self loop (w=1)

  const int e0 = offs[n], e1 = ends[n];
  int j = e0;
  for (; j + 8 <= e1; j += 8) {
    int s[8]; float w[8];
    #pragma unroll
    for (int u = 0; u < 8; ++u) { s[u] = csr_src[j + u]; w[u] = csr_norm[j + u]; }
    uint2 v[8];
    #pragma unroll
    for (int u = 0; u < 8; ++u) v[u] = x2[(size_t)s[u] * 32 + dq];
    #pragma unroll
    for (int u = 0; u < 8; ++u) fma4(acc, w[u], h8_to_f4(v[u]));
  }
  for (; j + 2 <= e1; j += 2) {
    int sa = csr_src[j], sb = csr_src[j + 1];
    float wa = csr_norm[j], wb = csr_norm[j + 1];
    uint2 va = x2[(size_t)sa * 32 + dq];
    uint2 vb = x2[(size_t)sb * 32 + dq];
    fma4(acc, wa, h8_to_f4(va)); fma4(acc, wb, h8_to_f4(vb));
  }
  if (j < e1) fma4(acc, csr_norm[j], h8_to_f4(x2[(size_t)csr_src[j] * 32 + dq]));

  const float4 b = *(const float4*)&bias[4 * dq];
  const float4 ti = ((const float4*)tin)[(size_t)n * 32 + dq];
  float4 o;
  o.x = (1.f - PRES) * (acc.x + b.x) + PRES * ti.x;
  o.y = (1.f - PRES) * (acc.y + b.y) + PRES * ti.y;
  o.z = (1.f - PRES) * (acc.z + b.z) + PRES * ti.z;
  o.w = (1.f - PRES) * (acc.w + b.w) + PRES * ti.w;
  ((float4*)out)[(size_t)n * 32 + dq] = o;
}

// ---------------- launch ----------------
extern "C" void kernel_launch(void* const* d_in, const int* in_sizes, int n_in,
                              void* d_out, int out_size, void* d_ws, size_t ws_size,
                              hipStream_t stream) {
  const float* demand = (const float*)d_in[0];
  const float* supply = (const float*)d_in[1];
  const int*   eidx   = (const int*)d_in[5];
  const float* eattr  = (const float*)d_in[6];
  const float* emb    = (const float*)d_in[10];
  const float* fuse_W = (const float*)d_in[11];
  const float* fuse_b = (const float*)d_in[12];
  const float* gcn_W  = (const float*)d_in[13];
  const float* gcn_b  = (const float*)d_in[14];
  float* outp = (float*)d_out;

  char* ws = (char*)d_ws;
  size_t o = 0;
  auto alloc = [&](size_t bytes) {
    char* p = ws + o;
    o += (bytes + 255) & ~(size_t)255;
    return p;
  };
  float* deg      = (float*)alloc((size_t)NN * 4);
  float* dinv     = (float*)alloc((size_t)NN * 4);
  int*   counts   = (int*)alloc((size_t)NN * 4);
  int*   lpre     = (int*)alloc((size_t)NN * 4);
  int*   bsum     = (int*)alloc(512);
  int*   bpre     = (int*)alloc(512);
  int*   offs     = (int*)alloc((size_t)NN * 4);
  int*   cursor   = (int*)alloc((size_t)NN * 4);
  int*   csr_src  = (int*)alloc((size_t)EE * 4);
  float* csr_norm = (float*)alloc((size_t)EE * 4);
  float* fuse_Wt  = (float*)alloc((size_t)384 * 128 * 4);
  float* gWt      = (float*)alloc((size_t)3 * 128 * 128 * 4);
  float* temp0    = (float*)alloc((size_t)NN * DD * 4);
  float* temp1    = (float*)alloc((size_t)NN * DD * 4);
  uint2* xh       = (uint2*)alloc((size_t)NN * DD * 2);   // fp16-packed x

  const int* srcv = eidx;        // edge_index[0]
  const int* dstv = eidx + EE;   // edge_index[1]

  const int NB = (NN + 255) / 256;   // 79
  const int EB = (EE + 255) / 256;   // 2500

  k_init<<<NB, 256, 0, stream>>>(deg, counts);
  k_edge_deg<<<EB, 256, 0, stream>>>(dstv, eattr, deg, counts);
  k_scan1<<<NB, 256, 0, stream>>>(counts, lpre, bsum);
  k_scan2<<<1, 128, 0, stream>>>(bsum, bpre, NB);
  k_scan3<<<NB, 256, 0, stream>>>(lpre, bpre, deg, offs, cursor, dinv);
  k_scatter<<<EB, 256, 0, stream>>>(srcv, dstv, eattr, dinv, cursor, csr_src, csr_norm);
  k_transpose_all<<<384, 256, 0, stream>>>(fuse_W, gcn_W, fuse_Wt, gWt);

  const int GB = (NN + G_BN - 1) / G_BN;  // 625
  // fused = [emb | demand[:, -1] | supply[:, -1]] @ fuse_W^T + fuse_b  (fp32 out)
  k_gemm<<<GB, 256, 0, stream>>>(emb, 128,
                                 demand + 11 * 128, TSEQ * 128,
                                 supply + 11 * 128, TSEQ * 128,
                                 3, fuse_Wt, fuse_b, temp0, nullptr);

  const int AB = (NN + 7) / 8;  // 2500
  // layer 0: temp0 -> temp1
  k_gemm<<<GB, 256, 0, stream>>>(temp0, 128, temp0, 128, temp0, 128, 1, gWt, nullptr, nullptr, xh);
  k_agg<<<AB, 256, 0, stream>>>(xh, temp0, offs, cursor, csr_src, csr_norm, dinv, gcn_b, temp1);
  // layer 1: temp1 -> temp0
  k_gemm<<<GB, 256, 0, stream>>>(temp1, 128, temp1, 128, temp1, 128, 1, gWt + 16384, nullptr, nullptr, xh);
  k_agg<<<AB, 256, 0, stream>>>(xh, temp1, offs, cursor, csr_src, csr_norm, dinv, gcn_b + 128, temp0);
  // layer 2: temp0 -> d_out
  k_gemm<<<GB, 256, 0, stream>>>(temp0, 128, temp0, 128, temp0, 128, 1, gWt + 32768, nullptr, nullptr, xh);
  k_agg<<<AB, 256, 0, stream>>>(xh, temp0, offs, cursor, csr_src, csr_norm, dinv, gcn_b + 256, outp);
}

// Round 3
// 460.744 us; speedup vs baseline: 1.2532x; 1.0916x over previous
//
#include <hip/hip_runtime.h>
#include <hip/hip_fp16.h>

#define NN 20000
#define DD 128
#define EE 640000
#define TSEQ 12
#define CAP 128          // per-node CSR bucket capacity (Poisson(32), 11 sigma)

__device__ __forceinline__ void fma4(float4& acc, float a, const float4& w) {
  acc.x += a * w.x; acc.y += a * w.y; acc.z += a * w.z; acc.w += a * w.w;
}

__device__ __forceinline__ float4 h8_to_f4(uint2 v) {
  union { unsigned u; __half2 h; } a, b;
  a.u = v.x; b.u = v.y;
  float2 fa = __half22float2(a.h);
  float2 fb = __half22float2(b.h);
  return make_float4(fa.x, fa.y, fb.x, fb.y);
}

__device__ __forceinline__ uint2 f4_to_h8(float4 o) {
  union { unsigned u; __half2 h; } a, b;
  a.h = __floats2half2_rn(o.x, o.y);
  b.h = __floats2half2_rn(o.z, o.w);
  uint2 r; r.x = a.u; r.y = b.u;
  return r;
}

// ---------------- setup ----------------
__global__ void k_init(float* __restrict__ deg, int* __restrict__ cnt) {
  int i = blockIdx.x * blockDim.x + threadIdx.x;
  if (i < NN) { deg[i] = 1.0f; cnt[i] = 0; }   // deg starts at 1 (self-loop)
}

// single edge pass: degree accumulate + bucket scatter of (src, w)
__global__ void k_edge(const int* __restrict__ src, const int* __restrict__ dst,
                       const float* __restrict__ w,
                       float* __restrict__ deg, int* __restrict__ cnt,
                       uint2* __restrict__ csr) {
  int e = blockIdx.x * blockDim.x + threadIdx.x;
  if (e < EE) {
    int s = src[e], d = dst[e];
    float we = w[e];
    atomicAdd(&deg[d], we);
    int slot = atomicAdd(&cnt[d], 1);
    if (slot < CAP) csr[(size_t)d * CAP + slot] = make_uint2((unsigned)s, __float_as_uint(we));
  }
}

// fuse_Wt fp32 [384][128]; gWt0 fp32 [128][128]; gWh fp16 [2][128][128] (layers 1,2), all k-major
__global__ void k_transpose_all(const float* __restrict__ fuse_W,
                                const float* __restrict__ gcn_W,
                                float* __restrict__ fuse_Wt,
                                float* __restrict__ gWt0,
                                __half* __restrict__ gWh) {
  int i = blockIdx.x * blockDim.x + threadIdx.x;
  if (i < 49152) {
    int k = i >> 7, d = i & 127;
    fuse_Wt[i] = fuse_W[d * 384 + k];
  } else if (i < 65536) {
    int j = i - 49152;
    int k = j >> 7, d = j & 127;
    gWt0[j] = gcn_W[d * 128 + k];
  } else if (i < 98304) {
    int j = i - 65536;
    int l = 1 + (j >> 14), jj = j & 16383;
    int k = jj >> 7, d = jj & 127;
    gWh[j] = (__half)gcn_W[l * 16384 + d * 128 + k];
  }
}

// ---------------- GEMM: out[n][d] = sum_k A[n][k] * Wt[k][d] (+bias) ----------------
#define G_TN 2
#define G_BN 32   // 16 dq-groups * 2 rows

__global__ __launch_bounds__(256, 4) void k_gemm(
    const float* __restrict__ a0, int s0,
    const float* __restrict__ a1, int s1,
    const float* __restrict__ a2, int s2,
    int nparts,
    const float* __restrict__ Wt,     // [nparts*128][128] (k-major)
    const float* __restrict__ bias,   // [128] or nullptr
    const float* __restrict__ deg_pm, // if non-null: premultiply row by rsqrt(deg[r])
    float* __restrict__ outf,         // fp32 out or nullptr
    uint2* __restrict__ outh)         // fp16-packed out or nullptr
{
  __shared__ float Ws[64 * 128];      // 32 KB: one 64-k chunk
  const int t = threadIdx.x;
  const int dq = t & 15;
  const int ng = t >> 4;
  const int n_base = blockIdx.x * G_BN + ng * G_TN;

  float4 acc0[G_TN], acc1[G_TN];
  #pragma unroll
  for (int i = 0; i < G_TN; ++i) {
    acc0[i] = make_float4(0.f, 0.f, 0.f, 0.f);
    acc1[i] = make_float4(0.f, 0.f, 0.f, 0.f);
  }

  for (int p = 0; p < nparts; ++p) {
    const float* ap; int as;
    if (p == 0) { ap = a0; as = s0; }
    else if (p == 1) { ap = a1; as = s1; }
    else { ap = a2; as = s2; }
    const float* rp[G_TN];
    #pragma unroll
    for (int i = 0; i < G_TN; ++i) {
      int r = n_base + i; if (r >= NN) r = NN - 1;
      rp[i] = ap + (size_t)r * as;
    }

    for (int c = 0; c < 2; ++c) {
      const float4* wsrc = (const float4*)(Wt + (p * 128 + c * 64) * 128);
      float4* wdst = (float4*)Ws;
      #pragma unroll
      for (int it = 0; it < 8; ++it) wdst[it * 256 + t] = wsrc[it * 256 + t];
      __syncthreads();

      const int ks = c * 64;
      for (int k = 0; k < 64; k += 4) {
        float4 av[G_TN];
        #pragma unroll
        for (int i = 0; i < G_TN; ++i) av[i] = *(const float4*)(rp[i] + ks + k);
        #pragma unroll
        for (int j = 0; j < 4; ++j) {
          const float4 w0 = *(const float4*)&Ws[(k + j) * 128 + 4 * dq];
          const float4 w1 = *(const float4*)&Ws[(k + j) * 128 + 64 + 4 * dq];
          #pragma unroll
          for (int i = 0; i < G_TN; ++i) {
            float a = (j == 0) ? av[i].x : (j == 1) ? av[i].y : (j == 2) ? av[i].z : av[i].w;
            fma4(acc0[i], a, w0);
            fma4(acc1[i], a, w1);
          }
        }
      }
      __syncthreads();
    }
  }

  float4 b0 = make_float4(0.f,0.f,0.f,0.f), b1 = b0;
  if (bias) {
    b0 = *(const float4*)&bias[4 * dq];
    b1 = *(const float4*)&bias[64 + 4 * dq];
  }
  #pragma unroll
  for (int i = 0; i < G_TN; ++i) {
    int r = n_base + i;
    if (r < NN) {
      float4 o0 = make_float4(acc0[i].x + b0.x, acc0[i].y + b0.y,
                              acc0[i].z + b0.z, acc0[i].w + b0.w);
      float4 o1 = make_float4(acc1[i].x + b1.x, acc1[i].y + b1.y,
                              acc1[i].z + b1.z, acc1[i].w + b1.w);
      if (outf) {
        *(float4*)(outf + (size_t)r * DD + 4 * dq) = o0;
        *(float4*)(outf + (size_t)r * DD + 64 + 4 * dq) = o1;
      } else {
        float di = rsqrtf(deg_pm[r]);
        o0.x *= di; o0.y *= di; o0.z *= di; o0.w *= di;
        o1.x *= di; o1.y *= di; o1.z *= di; o1.w *= di;
        outh[(size_t)r * 32 + dq] = f4_to_h8(o0);
        outh[(size_t)r * 32 + 16 + dq] = f4_to_h8(o1);
      }
    }
  }
}

// ---------------- fused aggregation (+ optional next-layer GEMM) ----------------
// xh holds dinv-premultiplied rows (fp16-packed).
// agg[n] = di * ( xh[n] + sum_e w_e * xh[src_e] );  out = 0.9*(agg+b) + 0.1*tin
// If NEXT: also x_next = out @ Wh^T (fp16 W), xh_out[n] = di * x_next (fp16)
template<bool NEXT>
__global__ __launch_bounds__(256, 4) void k_agg_fused(
    const uint2* __restrict__ xh, const float* __restrict__ tin,
    const int* __restrict__ cnt, const uint2* __restrict__ csr,
    const float* __restrict__ deg, const float* __restrict__ bias,
    const uint2* __restrict__ Wh,      // fp16-packed next W, k-major [128][32 uint2]
    float* __restrict__ tout,
    uint2* __restrict__ xh_out)
{
  __shared__ float rows[NEXT ? 8 * 128 : 8];
  __shared__ uint2 Whs[NEXT ? 4096 : 8];

  const int t = threadIdx.x;
  const int dq = t & 31;          // uint2 column (4 dims)
  const int nl = t >> 5;          // 8 nodes per block (20000 % 8 == 0)
  const int n = blockIdx.x * 8 + nl;

  // issue W staging loads early; stores happen after the edge loop (latency hidden)
  uint2 wreg[16];
  if constexpr (NEXT) {
    #pragma unroll
    for (int i = 0; i < 16; ++i) wreg[i] = Wh[i * 256 + t];
  }

  const float di = rsqrtf(deg[n]);
  float4 acc = h8_to_f4(xh[(size_t)n * 32 + dq]);   // self loop (weight 1, pre-di)

  const size_t base = (size_t)n * CAP;
  int m = cnt[n]; if (m > CAP) m = CAP;
  int j = 0;
  for (; j + 8 <= m; j += 8) {
    uint2 c[8];
    #pragma unroll
    for (int u = 0; u < 8; ++u) c[u] = csr[base + j + u];
    uint2 v[8];
    #pragma unroll
    for (int u = 0; u < 8; ++u) v[u] = xh[(size_t)c[u].x * 32 + dq];
    #pragma unroll
    for (int u = 0; u < 8; ++u) fma4(acc, __uint_as_float(c[u].y), h8_to_f4(v[u]));
  }
  for (; j < m; ++j) {
    uint2 c = csr[base + j];
    fma4(acc, __uint_as_float(c.y), h8_to_f4(xh[(size_t)c.x * 32 + dq]));
  }

  const float4 b4 = *(const float4*)&bias[4 * dq];
  const float4 ti = ((const float4*)tin)[(size_t)n * 32 + dq];
  float4 o;
  o.x = 0.9f * (di * acc.x + b4.x) + 0.1f * ti.x;
  o.y = 0.9f * (di * acc.y + b4.y) + 0.1f * ti.y;
  o.z = 0.9f * (di * acc.z + b4.z) + 0.1f * ti.z;
  o.w = 0.9f * (di * acc.w + b4.w) + 0.1f * ti.w;
  ((float4*)tout)[(size_t)n * 32 + dq] = o;

  if constexpr (NEXT) {
    #pragma unroll
    for (int i = 0; i < 16; ++i) Whs[i * 256 + t] = wreg[i];
    *(float4*)&rows[nl * 128 + 4 * dq] = o;
    __syncthreads();

    float4 x = make_float4(0.f, 0.f, 0.f, 0.f);
    const float* myrow = &rows[nl * 128];
    #pragma unroll 4
    for (int k = 0; k < 128; ++k) {
      fma4(x, myrow[k], h8_to_f4(Whs[k * 32 + dq]));
    }
    x.x *= di; x.y *= di; x.z *= di; x.w *= di;
    xh_out[(size_t)n * 32 + dq] = f4_to_h8(x);
  }
}

// ---------------- launch ----------------
extern "C" void kernel_launch(void* const* d_in, const int* in_sizes, int n_in,
                              void* d_out, int out_size, void* d_ws, size_t ws_size,
                              hipStream_t stream) {
  const float* demand = (const float*)d_in[0];
  const float* supply = (const float*)d_in[1];
  const int*   eidx   = (const int*)d_in[5];
  const float* eattr  = (const float*)d_in[6];
  const float* emb    = (const float*)d_in[10];
  const float* fuse_W = (const float*)d_in[11];
  const float* fuse_b = (const float*)d_in[12];
  const float* gcn_W  = (const float*)d_in[13];
  const float* gcn_b  = (const float*)d_in[14];
  float* outp = (float*)d_out;

  char* ws = (char*)d_ws;
  size_t o = 0;
  auto alloc = [&](size_t bytes) {
    char* p = ws + o;
    o += (bytes + 255) & ~(size_t)255;
    return p;
  };
  float*  deg     = (float*)alloc((size_t)NN * 4);
  int*    cnt     = (int*)alloc((size_t)NN * 4);
  uint2*  csr     = (uint2*)alloc((size_t)NN * CAP * 8);
  float*  fuse_Wt = (float*)alloc((size_t)384 * 128 * 4);
  float*  gWt0    = (float*)alloc((size_t)128 * 128 * 4);
  __half* gWh     = (__half*)alloc((size_t)2 * 128 * 128 * 2);
  float*  temp0   = (float*)alloc((size_t)NN * DD * 4);
  float*  temp1   = (float*)alloc((size_t)NN * DD * 4);
  uint2*  xh_a    = (uint2*)alloc((size_t)NN * DD * 2);
  uint2*  xh_b    = (uint2*)alloc((size_t)NN * DD * 2);

  const int* srcv = eidx;        // edge_index[0]
  const int* dstv = eidx + EE;   // edge_index[1]

  const int NB = (NN + 255) / 256;   // 79
  const int EB = (EE + 255) / 256;   // 2500

  k_init<<<NB, 256, 0, stream>>>(deg, cnt);
  k_edge<<<EB, 256, 0, stream>>>(srcv, dstv, eattr, deg, cnt, csr);
  k_transpose_all<<<384, 256, 0, stream>>>(fuse_W, gcn_W, fuse_Wt, gWt0, gWh);

  const int GB = (NN + G_BN - 1) / G_BN;  // 625
  // fused = [emb | demand[:,-1] | supply[:,-1]] @ fuse_W^T + fuse_b  (fp32)
  k_gemm<<<GB, 256, 0, stream>>>(emb, 128,
                                 demand + 11 * 128, TSEQ * 128,
                                 supply + 11 * 128, TSEQ * 128,
                                 3, fuse_Wt, fuse_b, nullptr, temp0, nullptr);
  // x0 = dinv * (temp0 @ W0^T)  (fp16)
  k_gemm<<<GB, 256, 0, stream>>>(temp0, 128, temp0, 128, temp0, 128,
                                 1, gWt0, nullptr, deg, nullptr, xh_a);

  const int AB = NN / 8;  // 2500
  k_agg_fused<true ><<<AB, 256, 0, stream>>>(xh_a, temp0, cnt, csr, deg, gcn_b,
                                             (const uint2*)gWh, temp1, xh_b);
  k_agg_fused<true ><<<AB, 256, 0, stream>>>(xh_b, temp1, cnt, csr, deg, gcn_b + 128,
                                             (const uint2*)(gWh + 16384), temp0, xh_a);
  k_agg_fused<false><<<AB, 256, 0, stream>>>(xh_a, temp0, cnt, csr, deg, gcn_b + 256,
                                             nullptr, outp, nullptr);
}

// Round 4
// 427.798 us; speedup vs baseline: 1.3497x; 1.0770x over previous
//
#include <hip/hip_runtime.h>
#include <hip/hip_fp16.h>

#define NN 20000
#define DD 128
#define EE 640000
#define TSEQ 12
#define CAP 128          // per-node CSR bucket capacity (Poisson(32), 11 sigma)
#define PADI 32          // counter padding: one counter per 128-byte line

__device__ __forceinline__ void fma4(float4& acc, float a, const float4& w) {
  acc.x += a * w.x; acc.y += a * w.y; acc.z += a * w.z; acc.w += a * w.w;
}

__device__ __forceinline__ float4 h8_to_f4(uint2 v) {
  union { unsigned u; __half2 h; } a, b;
  a.u = v.x; b.u = v.y;
  float2 fa = __half22float2(a.h);
  float2 fb = __half22float2(b.h);
  return make_float4(fa.x, fa.y, fb.x, fb.y);
}

__device__ __forceinline__ uint2 f4_to_h8(float4 o) {
  union { unsigned u; __half2 h; } a, b;
  a.h = __floats2half2_rn(o.x, o.y);
  b.h = __floats2half2_rn(o.z, o.w);
  uint2 r; r.x = a.u; r.y = b.u;
  return r;
}

// ---------------- prep: zero padded counters + all weight transposes ----------------
// blocks [0,625): deg_pad init (1.0 at slot 0 of each line, else 0)
// blocks [625,1250): cnt_pad zero
// blocks [1250,1634): transposes
__global__ void k_prep(const float* __restrict__ fuse_W,
                       const float* __restrict__ gcn_W,
                       float* __restrict__ deg_pad, int* __restrict__ cnt_pad,
                       float* __restrict__ fuse_Wt,
                       float* __restrict__ gWt0,
                       __half* __restrict__ gWh) {
  int b = blockIdx.x;
  if (b < 625) {
    int i = b * 256 + threadIdx.x;             // float4 slot; 160000 cover 640000 floats
    float4 z = make_float4((i & 7) == 0 ? 1.0f : 0.0f, 0.f, 0.f, 0.f);
    ((float4*)deg_pad)[i] = z;
  } else if (b < 1250) {
    int i = (b - 625) * 256 + threadIdx.x;
    ((int4*)cnt_pad)[i] = make_int4(0, 0, 0, 0);
  } else {
    int i = (b - 1250) * 256 + threadIdx.x;
    if (i < 49152) {
      int k = i >> 7, d = i & 127;
      fuse_Wt[i] = fuse_W[d * 384 + k];
    } else if (i < 65536) {
      int j = i - 49152;
      int k = j >> 7, d = j & 127;
      gWt0[j] = gcn_W[d * 128 + k];
    } else if (i < 98304) {
      int j = i - 65536;
      int l = 1 + (j >> 14), jj = j & 16383;
      int k = jj >> 7, d = jj & 127;
      gWh[j] = (__half)gcn_W[l * 16384 + d * 128 + k];
    }
  }
}

// ---------------- GEMM device body: out[n][d] = sum_k A[n][k]*Wt[k][d] (+bias) ------
#define G_TN 2
#define G_BN 32   // 16 dq-groups * 2 rows

__device__ __forceinline__ void gemm_body(
    float* Ws, int gb,
    const float* a0, int s0, const float* a1, int s1, const float* a2, int s2,
    int nparts, const float* Wt, const float* bias, const float* deg_pad,
    float* outf, uint2* outh)
{
  const int t = threadIdx.x;
  const int dq = t & 15;
  const int ng = t >> 4;
  const int n_base = gb * G_BN + ng * G_TN;

  float4 acc0[G_TN], acc1[G_TN];
  #pragma unroll
  for (int i = 0; i < G_TN; ++i) {
    acc0[i] = make_float4(0.f, 0.f, 0.f, 0.f);
    acc1[i] = make_float4(0.f, 0.f, 0.f, 0.f);
  }

  for (int p = 0; p < nparts; ++p) {
    const float* ap; int as;
    if (p == 0) { ap = a0; as = s0; }
    else if (p == 1) { ap = a1; as = s1; }
    else { ap = a2; as = s2; }
    const float* rp[G_TN];
    #pragma unroll
    for (int i = 0; i < G_TN; ++i) rp[i] = ap + (size_t)(n_base + i) * as;

    for (int c = 0; c < 2; ++c) {
      const float4* wsrc = (const float4*)(Wt + (p * 128 + c * 64) * 128);
      float4* wdst = (float4*)Ws;
      #pragma unroll
      for (int it = 0; it < 8; ++it) wdst[it * 256 + t] = wsrc[it * 256 + t];
      __syncthreads();

      const int ks = c * 64;
      for (int k = 0; k < 64; k += 4) {
        float4 av[G_TN];
        #pragma unroll
        for (int i = 0; i < G_TN; ++i) av[i] = *(const float4*)(rp[i] + ks + k);
        #pragma unroll
        for (int j = 0; j < 4; ++j) {
          const float4 w0 = *(const float4*)&Ws[(k + j) * 128 + 4 * dq];
          const float4 w1 = *(const float4*)&Ws[(k + j) * 128 + 64 + 4 * dq];
          #pragma unroll
          for (int i = 0; i < G_TN; ++i) {
            float a = (j == 0) ? av[i].x : (j == 1) ? av[i].y : (j == 2) ? av[i].z : av[i].w;
            fma4(acc0[i], a, w0);
            fma4(acc1[i], a, w1);
          }
        }
      }
      __syncthreads();
    }
  }

  float4 b0 = make_float4(0.f,0.f,0.f,0.f), b1 = b0;
  if (bias) {
    b0 = *(const float4*)&bias[4 * dq];
    b1 = *(const float4*)&bias[64 + 4 * dq];
  }
  #pragma unroll
  for (int i = 0; i < G_TN; ++i) {
    int r = n_base + i;
    float4 o0 = make_float4(acc0[i].x + b0.x, acc0[i].y + b0.y,
                            acc0[i].z + b0.z, acc0[i].w + b0.w);
    float4 o1 = make_float4(acc1[i].x + b1.x, acc1[i].y + b1.y,
                            acc1[i].z + b1.z, acc1[i].w + b1.w);
    if (outf) {
      *(float4*)(outf + (size_t)r * DD + 4 * dq) = o0;
      *(float4*)(outf + (size_t)r * DD + 64 + 4 * dq) = o1;
    } else {
      float di = rsqrtf(deg_pad[(size_t)r * PADI]);
      o0.x *= di; o0.y *= di; o0.z *= di; o0.w *= di;
      o1.x *= di; o1.y *= di; o1.z *= di; o1.w *= di;
      outh[(size_t)r * 32 + dq] = f4_to_h8(o0);
      outh[(size_t)r * 32 + 16 + dq] = f4_to_h8(o1);
    }
  }
}

// ---------------- mega: fuse-GEMM blocks [0,625) || edge blocks [625,3125) ----------
__global__ __launch_bounds__(256, 4) void k_mega(
    const float* __restrict__ emb, const float* __restrict__ demand,
    const float* __restrict__ supply,
    const float* __restrict__ fuse_Wt, const float* __restrict__ fuse_b,
    float* __restrict__ temp0,
    const int* __restrict__ src, const int* __restrict__ dst,
    const float* __restrict__ w,
    float* __restrict__ deg_pad, int* __restrict__ cnt_pad,
    uint2* __restrict__ csr)
{
  __shared__ float Ws[64 * 128];    // 32 KB (edge blocks carry it unused)
  if (blockIdx.x < 625) {
    gemm_body(Ws, blockIdx.x,
              emb, 128, demand + 11 * 128, TSEQ * 128, supply + 11 * 128, TSEQ * 128,
              3, fuse_Wt, fuse_b, nullptr, temp0, nullptr);
  } else {
    int e = (blockIdx.x - 625) * 256 + threadIdx.x;   // exactly EE threads
    int s = src[e], d = dst[e];
    float we = w[e];
    atomicAdd(&deg_pad[(size_t)d * PADI], we);
    int slot = atomicAdd(&cnt_pad[(size_t)d * PADI], 1);
    if (slot < CAP) csr[(size_t)d * CAP + slot] = make_uint2((unsigned)s, __float_as_uint(we));
  }
}

// ---------------- x0 GEMM: xh = rsqrt(deg)*(temp0 @ W0^T), fp16 ----------------
__global__ __launch_bounds__(256, 4) void k_gemm_x0(
    const float* __restrict__ temp0, const float* __restrict__ gWt0,
    const float* __restrict__ deg_pad, uint2* __restrict__ outh)
{
  __shared__ float Ws[64 * 128];
  gemm_body(Ws, blockIdx.x, temp0, 128, temp0, 128, temp0, 128,
            1, gWt0, nullptr, deg_pad, nullptr, outh);
}

// ---------------- fused aggregation (+ optional next-layer GEMM) ----------------
template<bool NEXT>
__global__ __launch_bounds__(256, 4) void k_agg_fused(
    const uint2* __restrict__ xh, const float* __restrict__ tin,
    const int* __restrict__ cnt_pad, const uint2* __restrict__ csr,
    const float* __restrict__ deg_pad, const float* __restrict__ bias,
    const uint2* __restrict__ Wh,      // fp16-packed next W, k-major [128][32 uint2]
    float* __restrict__ tout,
    uint2* __restrict__ xh_out)
{
  __shared__ float rows[NEXT ? 8 * 128 : 8];
  __shared__ uint2 Whs[NEXT ? 4096 : 8];

  const int t = threadIdx.x;
  const int dq = t & 31;          // uint2 column (4 dims)
  const int nl = t >> 5;          // 8 nodes per block
  const int n = blockIdx.x * 8 + nl;

  uint2 wreg[16];
  if constexpr (NEXT) {
    #pragma unroll
    for (int i = 0; i < 16; ++i) wreg[i] = Wh[i * 256 + t];
  }

  const float di = rsqrtf(deg_pad[(size_t)n * PADI]);
  float4 acc = h8_to_f4(xh[(size_t)n * 32 + dq]);   // self loop (weight 1, pre-di)

  const size_t base = (size_t)n * CAP;
  int m = cnt_pad[(size_t)n * PADI]; if (m > CAP) m = CAP;
  int j = 0;
  for (; j + 16 <= m; j += 16) {
    uint2 c[16];
    #pragma unroll
    for (int u = 0; u < 16; ++u) c[u] = csr[base + j + u];
    uint2 v[16];
    #pragma unroll
    for (int u = 0; u < 16; ++u) v[u] = xh[(size_t)c[u].x * 32 + dq];
    #pragma unroll
    for (int u = 0; u < 16; ++u) fma4(acc, __uint_as_float(c[u].y), h8_to_f4(v[u]));
  }
  for (; j + 4 <= m; j += 4) {
    uint2 c[4];
    #pragma unroll
    for (int u = 0; u < 4; ++u) c[u] = csr[base + j + u];
    uint2 v[4];
    #pragma unroll
    for (int u = 0; u < 4; ++u) v[u] = xh[(size_t)c[u].x * 32 + dq];
    #pragma unroll
    for (int u = 0; u < 4; ++u) fma4(acc, __uint_as_float(c[u].y), h8_to_f4(v[u]));
  }
  for (; j < m; ++j) {
    uint2 c = csr[base + j];
    fma4(acc, __uint_as_float(c.y), h8_to_f4(xh[(size_t)c.x * 32 + dq]));
  }

  const float4 b4 = *(const float4*)&bias[4 * dq];
  const float4 ti = ((const float4*)tin)[(size_t)n * 32 + dq];
  float4 o;
  o.x = 0.9f * (di * acc.x + b4.x) + 0.1f * ti.x;
  o.y = 0.9f * (di * acc.y + b4.y) + 0.1f * ti.y;
  o.z = 0.9f * (di * acc.z + b4.z) + 0.1f * ti.z;
  o.w = 0.9f * (di * acc.w + b4.w) + 0.1f * ti.w;
  ((float4*)tout)[(size_t)n * 32 + dq] = o;

  if constexpr (NEXT) {
    #pragma unroll
    for (int i = 0; i < 16; ++i) Whs[i * 256 + t] = wreg[i];
    *(float4*)&rows[nl * 128 + 4 * dq] = o;
    __syncthreads();

    float4 x = make_float4(0.f, 0.f, 0.f, 0.f);
    const float* myrow = &rows[nl * 128];
    #pragma unroll 4
    for (int k = 0; k < 128; ++k) {
      fma4(x, myrow[k], h8_to_f4(Whs[k * 32 + dq]));
    }
    x.x *= di; x.y *= di; x.z *= di; x.w *= di;
    xh_out[(size_t)n * 32 + dq] = f4_to_h8(x);
  }
}

// ---------------- launch ----------------
extern "C" void kernel_launch(void* const* d_in, const int* in_sizes, int n_in,
                              void* d_out, int out_size, void* d_ws, size_t ws_size,
                              hipStream_t stream) {
  const float* demand = (const float*)d_in[0];
  const float* supply = (const float*)d_in[1];
  const int*   eidx   = (const int*)d_in[5];
  const float* eattr  = (const float*)d_in[6];
  const float* emb    = (const float*)d_in[10];
  const float* fuse_W = (const float*)d_in[11];
  const float* fuse_b = (const float*)d_in[12];
  const float* gcn_W  = (const float*)d_in[13];
  const float* gcn_b  = (const float*)d_in[14];
  float* outp = (float*)d_out;

  char* ws = (char*)d_ws;
  size_t o = 0;
  auto alloc = [&](size_t bytes) {
    char* p = ws + o;
    o += (bytes + 255) & ~(size_t)255;
    return p;
  };
  float*  deg_pad = (float*)alloc((size_t)NN * PADI * 4);   // 2.56 MB
  int*    cnt_pad = (int*)alloc((size_t)NN * PADI * 4);     // 2.56 MB
  uint2*  csr     = (uint2*)alloc((size_t)NN * CAP * 8);
  float*  fuse_Wt = (float*)alloc((size_t)384 * 128 * 4);
  float*  gWt0    = (float*)alloc((size_t)128 * 128 * 4);
  __half* gWh     = (__half*)alloc((size_t)2 * 128 * 128 * 2);
  float*  temp0   = (float*)alloc((size_t)NN * DD * 4);
  float*  temp1   = (float*)alloc((size_t)NN * DD * 4);
  uint2*  xh_a    = (uint2*)alloc((size_t)NN * DD * 2);
  uint2*  xh_b    = (uint2*)alloc((size_t)NN * DD * 2);

  const int* srcv = eidx;        // edge_index[0]
  const int* dstv = eidx + EE;   // edge_index[1]

  k_prep<<<1634, 256, 0, stream>>>(fuse_W, gcn_W, deg_pad, cnt_pad, fuse_Wt, gWt0, gWh);

  k_mega<<<3125, 256, 0, stream>>>(emb, demand, supply, fuse_Wt, fuse_b, temp0,
                                   srcv, dstv, eattr, deg_pad, cnt_pad, csr);

  k_gemm_x0<<<625, 256, 0, stream>>>(temp0, gWt0, deg_pad, xh_a);

  const int AB = NN / 8;  // 2500
  k_agg_fused<true ><<<AB, 256, 0, stream>>>(xh_a, temp0, cnt_pad, csr, deg_pad, gcn_b,
                                             (const uint2*)gWh, temp1, xh_b);
  k_agg_fused<true ><<<AB, 256, 0, stream>>>(xh_b, temp1, cnt_pad, csr, deg_pad, gcn_b + 128,
                                             (const uint2*)(gWh + 16384), temp0, xh_a);
  k_agg_fused<false><<<AB, 256, 0, stream>>>(xh_a, temp0, cnt_pad, csr, deg_pad, gcn_b + 256,
                                             nullptr, outp, nullptr);
}